// Round 1
// baseline (496.321 us; speedup 1.0000x reference)
//
#include <hip/hip_runtime.h>

#define LL 64
#define DD 1024
#define HH 512
#define SS 50000
#define VV 40000
#define KD 32
#define MM 128  // B*L

typedef __bf16 bf16_t;
typedef __bf16 bf16x8 __attribute__((ext_vector_type(8)));
typedef __bf16 bf16x4 __attribute__((ext_vector_type(4)));
typedef float f32x4 __attribute__((ext_vector_type(4)));

// ---------------- Kernel 1: BatchNorm over (B, D) per l; write xn bf16 [128][1024]
__global__ __launch_bounds__(256) void k_bn(const float* __restrict__ x,
        const float* __restrict__ gamma, const float* __restrict__ beta,
        bf16_t* __restrict__ xn) {
    int l = blockIdx.x;        // 0..63
    int t = threadIdx.x;       // 0..255
    int b = t >> 7;            // 0..1
    int d0 = (t & 127) << 3;   // 8 elems/thread
    const float* xp = x + (size_t)(b * LL + l) * DD + d0;
    float4 v0 = *(const float4*)xp;
    float4 v1 = *(const float4*)(xp + 4);
    float s  = v0.x + v0.y + v0.z + v0.w + v1.x + v1.y + v1.z + v1.w;
    float ss = v0.x*v0.x + v0.y*v0.y + v0.z*v0.z + v0.w*v0.w
             + v1.x*v1.x + v1.y*v1.y + v1.z*v1.z + v1.w*v1.w;
    #pragma unroll
    for (int off = 32; off > 0; off >>= 1) {
        s  += __shfl_xor(s, off);
        ss += __shfl_xor(ss, off);
    }
    __shared__ float red[8];
    int wv = t >> 6, ln = t & 63;
    if (ln == 0) { red[wv] = s; red[4 + wv] = ss; }
    __syncthreads();
    float tot  = red[0] + red[1] + red[2] + red[3];
    float tots = red[4] + red[5] + red[6] + red[7];
    float mean = tot * (1.0f / 2048.0f);
    float var  = tots * (1.0f / 2048.0f) - mean * mean;
    float rstd = rsqrtf(var + 1e-5f);
    float g   = gamma[l] * rstd;
    float ofs = beta[l] - mean * g;
    bf16x8 o;
    o[0] = (bf16_t)(v0.x * g + ofs);
    o[1] = (bf16_t)(v0.y * g + ofs);
    o[2] = (bf16_t)(v0.z * g + ofs);
    o[3] = (bf16_t)(v0.w * g + ofs);
    o[4] = (bf16_t)(v1.x * g + ofs);
    o[5] = (bf16_t)(v1.y * g + ofs);
    o[6] = (bf16_t)(v1.z * g + ofs);
    o[7] = (bf16_t)(v1.w * g + ofs);
    *(bf16x8*)(xn + (size_t)(b * LL + l) * DD + d0) = o;
}

// ---------------- Kernel 2: h = relu(xn @ W1 + b1), bf16 [128][512]
__global__ __launch_bounds__(256) void k_gemm1(const bf16_t* __restrict__ xn,
        const float* __restrict__ W1, const float* __restrict__ b1,
        bf16_t* __restrict__ h) {
    int t = threadIdx.x;
    int wv = t >> 6, lane = t & 63;
    int c = lane & 15, q = lane >> 4;
    int tile = blockIdx.x * 4 + wv;  // 256 tiles: 8 m x 32 n
    int tm = tile >> 5, tn = tile & 31;
    int col = tn * 16 + c;
    f32x4 acc = {};
    for (int kk = 0; kk < DD; kk += 32) {
        bf16x8 afr = *(const bf16x8*)(xn + (size_t)(tm * 16 + c) * DD + kk + q * 8);
        bf16x8 bfr;
        #pragma unroll
        for (int j = 0; j < 8; ++j)
            bfr[j] = (bf16_t)W1[(size_t)(kk + q * 8 + j) * HH + col];
        acc = __builtin_amdgcn_mfma_f32_16x16x32_bf16(afr, bfr, acc, 0, 0, 0);
    }
    float bias = b1[col];
    #pragma unroll
    for (int r = 0; r < 4; ++r) {
        int m = tm * 16 + q * 4 + r;   // C/D: col=lane&15, row=q*4+r  [m89]
        float v = acc[r] + bias;
        h[(size_t)m * HH + col] = (bf16_t)(v > 0.f ? v : 0.f);
    }
}

// ---------------- Kernel 3: vT[col][m] = bf16(h @ W_slm + b_slm), transposed
__global__ __launch_bounds__(256) void k_gemm_v(const bf16_t* __restrict__ h,
        const float* __restrict__ Wslm, const float* __restrict__ bslm,
        bf16_t* __restrict__ vT) {
    int t = threadIdx.x;
    int wv = t >> 6, lane = t & 63;
    int c = lane & 15, q = lane >> 4;
    int col = blockIdx.x * 64 + wv * 16 + c;   // 40000 = 625*64, exact
    f32x4 acc[8] = {};
    for (int kk = 0; kk < HH; kk += 32) {
        bf16x8 bfr;
        #pragma unroll
        for (int j = 0; j < 8; ++j)
            bfr[j] = (bf16_t)Wslm[(size_t)(kk + q * 8 + j) * VV + col];
        #pragma unroll
        for (int ms = 0; ms < 8; ++ms) {
            bf16x8 afr = *(const bf16x8*)(h + (size_t)(ms * 16 + c) * HH + kk + q * 8);
            acc[ms] = __builtin_amdgcn_mfma_f32_16x16x32_bf16(afr, bfr, acc[ms], 0, 0, 0);
        }
    }
    float bias = bslm[col];
    #pragma unroll
    for (int ms = 0; ms < 8; ++ms) {
        bf16x4 o;
        #pragma unroll
        for (int r = 0; r < 4; ++r) o[r] = (bf16_t)(acc[ms][r] + bias);
        *(bf16x4*)(vT + (size_t)col * MM + ms * 16 + q * 4) = o;
    }
}

// ---------------- Kernel 4: out = h @ W2 + b2 + 0.1 * gather(vT, sl_idx, sl_w)
__global__ __launch_bounds__(256) void k_gemm_y(const bf16_t* __restrict__ h,
        const float* __restrict__ W2, const float* __restrict__ b2,
        const bf16_t* __restrict__ vT, const float* __restrict__ slw,
        const int* __restrict__ slidx, float* __restrict__ out) {
    int t = threadIdx.x;
    int wv = t >> 6, lane = t & 63;
    int c = lane & 15, q = lane >> 4;
    int nb = blockIdx.x * 64;
    int col = nb + wv * 16 + c;
    int colc = col < SS ? col : SS - 1;     // clamp for tail block loads
    f32x4 acc[8] = {};
    for (int kk = 0; kk < HH; kk += 32) {
        bf16x8 bfr;
        #pragma unroll
        for (int j = 0; j < 8; ++j)
            bfr[j] = (bf16_t)W2[(size_t)(kk + q * 8 + j) * SS + colc];
        #pragma unroll
        for (int ms = 0; ms < 8; ++ms) {
            bf16x8 afr = *(const bf16x8*)(h + (size_t)(ms * 16 + c) * HH + kk + q * 8);
            acc[ms] = __builtin_amdgcn_mfma_f32_16x16x32_bf16(afr, bfr, acc[ms], 0, 0, 0);
        }
    }
    // ---- gather phase: slm[n_loc][m] = sum_k w[s,k] * vT[idx[s,k]][m]
    __shared__ float slm[64 * 129];
    int n_loc = t & 63;          // lane-distinct within a wave -> conflict-free writes
    int m0 = (t >> 6) * 32;      // each wave owns a 32-row m chunk
    int s = nb + n_loc; if (s >= SS) s = SS - 1;
    float accg[32];
    #pragma unroll
    for (int i = 0; i < 32; ++i) accg[i] = 0.f;
    for (int k = 0; k < KD; ++k) {
        int id  = slidx[(size_t)s * KD + k];
        float w = slw[(size_t)s * KD + k];
        const bf16_t* vr = vT + (size_t)id * MM + m0;
        #pragma unroll
        for (int j = 0; j < 4; ++j) {
            bf16x8 vv = *(const bf16x8*)(vr + j * 8);
            #pragma unroll
            for (int e = 0; e < 8; ++e)
                accg[j * 8 + e] += w * (float)vv[e];
        }
    }
    #pragma unroll
    for (int i = 0; i < 32; ++i) slm[n_loc * 129 + m0 + i] = accg[i];
    __syncthreads();
    // ---- epilogue: combine and store
    if (col < SS) {
        float bias = b2[col];
        #pragma unroll
        for (int ms = 0; ms < 8; ++ms) {
            #pragma unroll
            for (int r = 0; r < 4; ++r) {
                int m = ms * 16 + q * 4 + r;
                out[(size_t)m * SS + col] = acc[ms][r] + bias
                                          + 0.1f * slm[(wv * 16 + c) * 129 + m];
            }
        }
    }
}

extern "C" void kernel_launch(void* const* d_in, const int* in_sizes, int n_in,
                              void* d_out, int out_size, void* d_ws, size_t ws_size,
                              hipStream_t stream) {
    const float* x     = (const float*)d_in[0];
    const float* gamma = (const float*)d_in[1];
    const float* beta  = (const float*)d_in[2];
    const float* W1    = (const float*)d_in[3];
    const float* b1    = (const float*)d_in[4];
    const float* W2    = (const float*)d_in[5];
    const float* b2    = (const float*)d_in[6];
    const float* Wslm  = (const float*)d_in[7];
    const float* bslm  = (const float*)d_in[8];
    const float* slw   = (const float*)d_in[9];
    const int*   slidx = (const int*)d_in[10];
    float* out = (float*)d_out;

    char* ws = (char*)d_ws;
    bf16_t* xn = (bf16_t*)ws;                  // 128*1024*2 = 256 KB
    bf16_t* h  = (bf16_t*)(ws + 262144);       // 128*512*2  = 128 KB
    bf16_t* vT = (bf16_t*)(ws + 393216);       // 40000*128*2 = 10.24 MB

    k_bn    <<<64,  256, 0, stream>>>(x, gamma, beta, xn);
    k_gemm1 <<<64,  256, 0, stream>>>(xn, W1, b1, h);
    k_gemm_v<<<625, 256, 0, stream>>>(h, Wslm, bslm, vT);
    k_gemm_y<<<782, 256, 0, stream>>>(h, W2, b2, vT, slw, slidx, out);
}

// Round 3
// 352.305 us; speedup vs baseline: 1.4088x; 1.4088x over previous
//
#include <hip/hip_runtime.h>

#define LL 64
#define DD 1024
#define HH 512
#define SS 50000
#define VV 40000
#define KD 32
#define MM 128  // B*L

typedef __bf16 bf16_t;
typedef __bf16 bf16x8 __attribute__((ext_vector_type(8)));
typedef __bf16 bf16x4 __attribute__((ext_vector_type(4)));
typedef __bf16 bf16x2 __attribute__((ext_vector_type(2)));
typedef float f32x4 __attribute__((ext_vector_type(4)));

__device__ __forceinline__ void async_ld16(const void* g, void* l) {
    __builtin_amdgcn_global_load_lds(
        (const __attribute__((address_space(1))) void*)g,
        (__attribute__((address_space(3))) void*)l, 16, 0, 0);
}

// ---------------- Kernel 1: BatchNorm over (B, D) per l; write xn bf16 [128][1024]
__global__ __launch_bounds__(256) void k_bn(const float* __restrict__ x,
        const float* __restrict__ gamma, const float* __restrict__ beta,
        bf16_t* __restrict__ xn) {
    int l = blockIdx.x;        // 0..63
    int t = threadIdx.x;       // 0..255
    int b = t >> 7;            // 0..1
    int d0 = (t & 127) << 3;   // 8 elems/thread
    const float* xp = x + (size_t)(b * LL + l) * DD + d0;
    float4 v0 = *(const float4*)xp;
    float4 v1 = *(const float4*)(xp + 4);
    float s  = v0.x + v0.y + v0.z + v0.w + v1.x + v1.y + v1.z + v1.w;
    float ss = v0.x*v0.x + v0.y*v0.y + v0.z*v0.z + v0.w*v0.w
             + v1.x*v1.x + v1.y*v1.y + v1.z*v1.z + v1.w*v1.w;
    #pragma unroll
    for (int off = 32; off > 0; off >>= 1) {
        s  += __shfl_xor(s, off);
        ss += __shfl_xor(ss, off);
    }
    __shared__ float red[8];
    int wv = t >> 6, ln = t & 63;
    if (ln == 0) { red[wv] = s; red[4 + wv] = ss; }
    __syncthreads();
    float tot  = red[0] + red[1] + red[2] + red[3];
    float tots = red[4] + red[5] + red[6] + red[7];
    float mean = tot * (1.0f / 2048.0f);
    float var  = tots * (1.0f / 2048.0f) - mean * mean;
    float rstd = rsqrtf(var + 1e-5f);
    float g   = gamma[l] * rstd;
    float ofs = beta[l] - mean * g;
    bf16x8 o;
    o[0] = (bf16_t)(v0.x * g + ofs);
    o[1] = (bf16_t)(v0.y * g + ofs);
    o[2] = (bf16_t)(v0.z * g + ofs);
    o[3] = (bf16_t)(v0.w * g + ofs);
    o[4] = (bf16_t)(v1.x * g + ofs);
    o[5] = (bf16_t)(v1.y * g + ofs);
    o[6] = (bf16_t)(v1.z * g + ofs);
    o[7] = (bf16_t)(v1.w * g + ofs);
    *(bf16x8*)(xn + (size_t)(b * LL + l) * DD + d0) = o;
}

// ---------------- Kernel 2: h = relu(xn @ W1 + b1), bf16 [128][512]
__global__ __launch_bounds__(256) void k_gemm1(const bf16_t* __restrict__ xn,
        const float* __restrict__ W1, const float* __restrict__ b1,
        bf16_t* __restrict__ h) {
    int t = threadIdx.x;
    int wv = t >> 6, lane = t & 63;
    int c = lane & 15, q = lane >> 4;
    int tile = blockIdx.x * 4 + wv;  // 256 tiles: 8 m x 32 n
    int tm = tile >> 5, tn = tile & 31;
    int col = tn * 16 + c;
    f32x4 acc = {};
    for (int kk = 0; kk < DD; kk += 32) {
        bf16x8 afr = *(const bf16x8*)(xn + (size_t)(tm * 16 + c) * DD + kk + q * 8);
        bf16x8 bfr;
        #pragma unroll
        for (int j = 0; j < 8; ++j)
            bfr[j] = (bf16_t)W1[(size_t)(kk + q * 8 + j) * HH + col];
        acc = __builtin_amdgcn_mfma_f32_16x16x32_bf16(afr, bfr, acc, 0, 0, 0);
    }
    float bias = b1[col];
    #pragma unroll
    for (int r = 0; r < 4; ++r) {
        int m = tm * 16 + q * 4 + r;   // C/D: col=lane&15, row=q*4+r  [m89]
        float v = acc[r] + bias;
        h[(size_t)m * HH + col] = (bf16_t)(v > 0.f ? v : 0.f);
    }
}

// ---------------- Kernel 3: vT[col][m] = bf16(h @ W_slm + b_slm), transposed
// Double-buffered LDS W-tile via global_load_lds width=16.
// Tile = 32 k-rows x 64 cols fp32 = 8192 B -> each thread stages TWO 16B chunks.
__global__ __launch_bounds__(256) void k_gemm_v(const bf16_t* __restrict__ h,
        const float* __restrict__ Wslm, const float* __restrict__ bslm,
        bf16_t* __restrict__ vT) {
    __shared__ float wt[2][32 * 64];   // [buf][k=32][col=64] fp32, 16 KB
    int t = threadIdx.x;
    int wv = t >> 6, lane = t & 63;
    int c = lane & 15, q = lane >> 4;
    int nb = blockIdx.x * 64;          // 40000 = 625*64, exact
    int col = nb + wv * 16 + c;
    int r  = t >> 4, sg = t & 15;      // r in 0..15; stage rows r and r+16
    const float* g0 = Wslm + (size_t)r        * VV + nb + sg * 4;
    const float* g1 = Wslm + (size_t)(r + 16) * VV + nb + sg * 4;

    #define STAGE_V(buf, kk) do { \
        async_ld16(g0 + (size_t)(kk) * VV, &wt[buf][t * 4]); \
        async_ld16(g1 + (size_t)(kk) * VV, &wt[buf][(t + 256) * 4]); } while (0)

    STAGE_V(0, 0);
    f32x4 acc[8] = {};
    #pragma unroll 1
    for (int step = 0; step < 16; ++step) {
        int cur = step & 1;
        __syncthreads();                       // drains vmcnt -> wt[cur] ready
        if (step < 15) STAGE_V(cur ^ 1, (step + 1) * 32);
        int kk = step * 32;
        bf16x8 bfr;
        #pragma unroll
        for (int j = 0; j < 8; ++j)
            bfr[j] = (bf16_t)wt[cur][(q * 8 + j) * 64 + wv * 16 + c];
        #pragma unroll
        for (int ms = 0; ms < 8; ++ms) {
            bf16x8 afr = *(const bf16x8*)(h + (size_t)(ms * 16 + c) * HH + kk + q * 8);
            acc[ms] = __builtin_amdgcn_mfma_f32_16x16x32_bf16(afr, bfr, acc[ms], 0, 0, 0);
        }
    }
    float bias = bslm[col];
    #pragma unroll
    for (int ms = 0; ms < 8; ++ms) {
        bf16x4 o;
        #pragma unroll
        for (int rr = 0; rr < 4; ++rr) o[rr] = (bf16_t)(acc[ms][rr] + bias);
        *(bf16x4*)(vT + (size_t)col * MM + ms * 16 + q * 4) = o;
    }
    #undef STAGE_V
}

// ---------------- Kernel 4: gather — one wave per s, lane owns 2 m-values.
// slm[s][m] (bf16) = sum_k w[s,k] * vT[idx[s,k]][m]
__global__ __launch_bounds__(256) void k_gather(const bf16_t* __restrict__ vT,
        const float* __restrict__ slw, const int* __restrict__ slidx,
        bf16_t* __restrict__ slm) {
    int t = threadIdx.x;
    int wv = t >> 6, lane = t & 63;
    int s = blockIdx.x * 4 + wv;        // 50000 = 12500*4, exact
    int idv = slidx[(size_t)s * KD + (lane & 31)];
    float wgt = slw[(size_t)s * KD + (lane & 31)];
    unsigned int u[KD];
    #pragma unroll
    for (int k = 0; k < KD; ++k) {
        int id = __shfl(idv, k);
        u[k] = *(const unsigned int*)(vT + (size_t)id * MM + lane * 2);
    }
    float a0 = 0.f, a1 = 0.f;
    #pragma unroll
    for (int k = 0; k < KD; ++k) {
        float w = __shfl(wgt, k);
        a0 += w * __uint_as_float(u[k] << 16);
        a1 += w * __uint_as_float(u[k] & 0xffff0000u);
    }
    bf16x2 o;
    o[0] = (bf16_t)a0;
    o[1] = (bf16_t)a1;
    *(bf16x2*)(slm + (size_t)s * MM + lane * 2) = o;
}

// ---------------- Kernel 5: out = h @ W2 + b2 + 0.1 * slm^T
__global__ __launch_bounds__(256) void k_gemm_y(const bf16_t* __restrict__ h,
        const float* __restrict__ W2, const float* __restrict__ b2,
        const bf16_t* __restrict__ slm, float* __restrict__ out) {
    __shared__ float wt[2][32 * 64];   // 16 KB
    int t = threadIdx.x;
    int wv = t >> 6, lane = t & 63;
    int c = lane & 15, q = lane >> 4;
    int nb = blockIdx.x * 64;
    int col = nb + wv * 16 + c;
    int r  = t >> 4, sg = t & 15;
    int sgc = nb + sg * 4;             // first of 4 cols this lane stages
    bool ok = (sgc + 4 <= SS);
    const float* g0 = ok ? (W2 + (size_t)r        * SS + sgc) : W2;
    const float* g1 = ok ? (W2 + (size_t)(r + 16) * SS + sgc) : W2;

    #define STAGE_Y(buf, kk) do { \
        async_ld16(g0 + (size_t)(kk) * SS, &wt[buf][t * 4]); \
        async_ld16(g1 + (size_t)(kk) * SS, &wt[buf][(t + 256) * 4]); } while (0)

    STAGE_Y(0, 0);
    f32x4 acc[8] = {};
    #pragma unroll 1
    for (int step = 0; step < 16; ++step) {
        int cur = step & 1;
        __syncthreads();
        if (step < 15) STAGE_Y(cur ^ 1, (step + 1) * 32);
        int kk = step * 32;
        bf16x8 bfr;
        #pragma unroll
        for (int j = 0; j < 8; ++j)
            bfr[j] = (bf16_t)wt[cur][(q * 8 + j) * 64 + wv * 16 + c];
        #pragma unroll
        for (int ms = 0; ms < 8; ++ms) {
            bf16x8 afr = *(const bf16x8*)(h + (size_t)(ms * 16 + c) * HH + kk + q * 8);
            acc[ms] = __builtin_amdgcn_mfma_f32_16x16x32_bf16(afr, bfr, acc[ms], 0, 0, 0);
        }
    }
    if (col < SS) {
        float bias = b2[col];
        #pragma unroll
        for (int ms = 0; ms < 8; ++ms) {
            bf16x4 sv = *(const bf16x4*)(slm + (size_t)col * MM + ms * 16 + q * 4);
            #pragma unroll
            for (int rr = 0; rr < 4; ++rr) {
                int m = ms * 16 + q * 4 + rr;
                out[(size_t)m * SS + col] = acc[ms][rr] + bias + 0.1f * (float)sv[rr];
            }
        }
    }
    #undef STAGE_Y
}

extern "C" void kernel_launch(void* const* d_in, const int* in_sizes, int n_in,
                              void* d_out, int out_size, void* d_ws, size_t ws_size,
                              hipStream_t stream) {
    const float* x     = (const float*)d_in[0];
    const float* gamma = (const float*)d_in[1];
    const float* beta  = (const float*)d_in[2];
    const float* W1    = (const float*)d_in[3];
    const float* b1    = (const float*)d_in[4];
    const float* W2    = (const float*)d_in[5];
    const float* b2    = (const float*)d_in[6];
    const float* Wslm  = (const float*)d_in[7];
    const float* bslm  = (const float*)d_in[8];
    const float* slw   = (const float*)d_in[9];
    const int*   slidx = (const int*)d_in[10];
    float* out = (float*)d_out;

    char* ws = (char*)d_ws;
    bf16_t* xn  = (bf16_t*)ws;                     // 128*1024*2  = 262144 B
    bf16_t* h   = (bf16_t*)(ws + 262144);          // 128*512*2   = 131072 B
    bf16_t* vT  = (bf16_t*)(ws + 393216);          // 40000*128*2 = 10240000 B
    bf16_t* slm = (bf16_t*)(ws + 10633216);        // 50000*128*2 = 12800000 B

    k_bn    <<<64,    256, 0, stream>>>(x, gamma, beta, xn);
    k_gemm1 <<<64,    256, 0, stream>>>(xn, W1, b1, h);
    k_gemm_v<<<625,   256, 0, stream>>>(h, Wslm, bslm, vT);
    k_gather<<<12500, 256, 0, stream>>>(vT, slw, slidx, slm);
    k_gemm_y<<<782,   256, 0, stream>>>(h, W2, b2, slm, out);
}